// Round 9
// baseline (290.210 us; speedup 1.0000x reference)
//
#include <hip/hip_runtime.h>
#include <hip/hip_fp16.h>
#include <math.h>

#define LRELU_ALPHA 0.2f

constexpr int B_ = 8, N_ = 2048, FIN = 128, FOUT = 64;

typedef _Float16 f16x2 __attribute__((ext_vector_type(2)));
typedef _Float16 f16x8 __attribute__((ext_vector_type(8)));
typedef float f32x4 __attribute__((ext_vector_type(4)));

__device__ __forceinline__ unsigned short f2h(float x) {
  return __half_as_ushort(__float2half(x));
}

// ---------------------------------------------------------------------------
// Kernel 1 (fused): blocks 0..1023 = wh role (Wh = h@W^T -> WhT fp16 [b][o][n]
// + separable-exp factors); blocks 1024..5119 = pack role (adj -> 1 bit).
// Fusing lets wh's compute overlap pack's 134 MB HBM stream and removes one
// launch gap. p = exp(lrelu(s1+s2)-2) = max(E1p*E2p, E1n*E2n) (exp monotone).
// ---------------------------------------------------------------------------
__global__ __launch_bounds__(256) void k_prep(
    const float* __restrict__ h, const float* __restrict__ W,
    const float* __restrict__ a, const int* __restrict__ adj,
    unsigned short* __restrict__ WhT, unsigned int* __restrict__ e1h2,
    unsigned short* __restrict__ e2ps, unsigned short* __restrict__ e2ns,
    unsigned int* __restrict__ bits) {
  const int t = threadIdx.x;
  const int bx = blockIdx.x;

  if (bx >= 1024) {  // ---- pack role (validated R6-R8) ----
    const size_t g = (size_t)(bx - 1024) * 256 + t;
    const int4* src = (const int4*)adj + g * 8;
    int4 v[8];
#pragma unroll
    for (int c = 0; c < 8; ++c) v[c] = src[c];
    unsigned int w = 0;
#pragma unroll
    for (int c = 0; c < 8; ++c) {
      w |= (v[c].x != 0 ? 1u : 0u) << (c * 4 + 0);
      w |= (v[c].y != 0 ? 1u : 0u) << (c * 4 + 1);
      w |= (v[c].z != 0 ? 1u : 0u) << (c * 4 + 2);
      w |= (v[c].w != 0 ? 1u : 0u) << (c * 4 + 3);
    }
    bits[g] = w;
    return;
  }

  // ---- wh role ----
  __shared__ float Wt[128][65];  // [f][o]: bank (f+o)%32 -> conflict-free
  __shared__ float hs[16][128];
  const int row0 = bx * 16;

  for (int e = t; e < 64 * 128; e += 256) {
    int o = e >> 7, f = e & 127;
    Wt[f][o] = W[e];
  }
  {
    const float4* hg = (const float4*)(h + (size_t)row0 * FIN);
    for (int i4 = t; i4 < 16 * 32; i4 += 256) {
      int r = i4 >> 5, f4 = i4 & 31;
      *(float4*)&hs[r][f4 * 4] = hg[i4];
    }
  }
  __syncthreads();

  const int wave = t >> 6, lane = t & 63;  // lane = o
  float acc[4] = {0.f, 0.f, 0.f, 0.f};
#pragma unroll 4
  for (int f4 = 0; f4 < 32; ++f4) {
    float w0 = Wt[4 * f4 + 0][lane], w1 = Wt[4 * f4 + 1][lane];
    float w2 = Wt[4 * f4 + 2][lane], w3 = Wt[4 * f4 + 3][lane];
#pragma unroll
    for (int r = 0; r < 4; ++r) {
      float4 hv = *(const float4*)&hs[wave * 4 + r][f4 * 4];
      acc[r] += hv.x * w0 + hv.y * w1 + hv.z * w2 + hv.w * w3;
    }
  }

  const float a1v = a[lane], a2v = a[64 + lane];
  const int b = row0 / N_;
#pragma unroll
  for (int r = 0; r < 4; ++r) {
    const int row = row0 + wave * 4 + r;  // = b*N + n
    const int n = row - b * N_;
    const float v = acc[r];
    WhT[((size_t)b * 64 + lane) * N_ + n] = f2h(v);
    float p1 = v * a1v, p2 = v * a2v;
#pragma unroll
    for (int d = 32; d; d >>= 1) {
      p1 += __shfl_xor(p1, d, 64);
      p2 += __shfl_xor(p2, d, 64);
    }
    if (lane == 0) {
      e1h2[row] = (unsigned int)f2h(__expf(p1 - 1.0f)) |
                  ((unsigned int)f2h(__expf(LRELU_ALPHA * p1 - 1.0f)) << 16);
      e2ps[row] = f2h(__expf(p2 - 1.0f));
      e2ns[row] = f2h(__expf(LRELU_ALPHA * p2 - 1.0f));
    }
  }
}

// ---------------------------------------------------------------------------
// Kernel 2: attention, full-j per block -> direct out write (no partials,
// no reduce kernel). Block = 16 i-rows x 64 o x all 2048 j; grid (128,8) =
// 1024 blocks, LDS 24 KB, ~60 VGPR -> 4 blocks/CU = 4 waves/SIMD (2x R8's
// latency hiding). Wave = one o-group (P-gen dup x4: +VALU for +occupancy).
// j loop: 16 strips of 128 j; strip staged in LDS (16 KB, XOR-swizzled ->
// all ds traffic <=2-way = free); next strip's global loads issued into
// VGPRs right after ds_write, in flight through the strip's compute.
// lsum via ones-MFMA accumulates the FULL row sum -> normalize in epilogue.
// ---------------------------------------------------------------------------
__global__ __launch_bounds__(256, 4) void k_attn(
    const unsigned short* __restrict__ WhT,
    const unsigned int* __restrict__ e1h2,
    const unsigned short* __restrict__ e2ps,
    const unsigned short* __restrict__ e2ns,
    const unsigned int* __restrict__ bits, float* __restrict__ out) {
  __shared__ __align__(16) unsigned short whs[64 * 128];  // 16 KB swizzled
  __shared__ __align__(16) unsigned short e2sp_[N_];      // 4 KB
  __shared__ __align__(16) unsigned short e2sn_[N_];      // 4 KB

  const int t = threadIdx.x;
  const int g = t >> 6, lane = t & 63;  // g = this wave's o-group
  const int m = lane & 15, q = lane >> 4;
  const int b = blockIdx.y, i0 = blockIdx.x * 16;

  // stage full e2 rows (2048 ushort each = 256 uint4)
  ((uint4*)e2sp_)[t] = ((const uint4*)(e2ps + (size_t)b * N_))[t];
  ((uint4*)e2sn_)[t] = ((const uint4*)(e2ns + (size_t)b * N_))[t];

  const int row = i0 + m;  // this lane's A-row
  const f16x2 e1 = __builtin_bit_cast(f16x2, e1h2[b * N_ + row]);
  const uint4* bitp = (const uint4*)(bits + ((size_t)(b * N_ + row)) * 64);

  // strip staging: thread t owns chunk ids l*256+t (o = id>>4, c = id&15);
  // swizzle: chunk c of row o lands at c^(o&15) -> B-frag reads 2-way max.
  const unsigned short* whB = WhT + (size_t)b * 64 * N_;
  size_t gsrc[4];
  int ldst[4];
#pragma unroll
  for (int l = 0; l < 4; ++l) {
    const int id = l * 256 + t;
    const int o = id >> 4, c = id & 15;
    gsrc[l] = (size_t)o * N_ + c * 8;
    ldst[l] = o * 256 + ((c ^ (o & 15)) << 4);  // bytes
  }
  uint4 pf[4];
#pragma unroll
  for (int l = 0; l < 4; ++l) pf[l] = *(const uint4*)(whB + gsrc[l]);

  f32x4 acc = {0.f, 0.f, 0.f, 0.f}, lf = acc;
  const f16x8 ones = {1, 1, 1, 1, 1, 1, 1, 1};
  const int bfo = (g * 16 + m) * 256;  // B-frag row base (bytes)

#pragma unroll 1  // keep body ~1.6 KB (R6 I-cache lesson)
  for (int s = 0; s < 16; ++s) {
#pragma unroll
    for (int l = 0; l < 4; ++l) *(uint4*)((char*)whs + ldst[l]) = pf[l];
    __syncthreads();  // strip visible (also covers e2 fill on s=0)
    if (s < 15) {     // prefetch next strip; in flight through compute
#pragma unroll
      for (int l = 0; l < 4; ++l)
        pf[l] = *(const uint4*)(whB + gsrc[l] + (s + 1) * 128);
    }
    const uint4 wq4 = bitp[s];  // 4 bit-words = this strip's 128 j for row m

#pragma unroll
    for (int ks = 0; ks < 4; ++ks) {
      const unsigned int word =
          (ks == 0 ? wq4.x : ks == 1 ? wq4.y : ks == 2 ? wq4.z : wq4.w) >>
          (q * 8);
      const f16x8 e2pv = *(const f16x8*)&e2sp_[s * 128 + ks * 32 + q * 8];
      const f16x8 e2nv = *(const f16x8*)&e2sn_[s * 128 + ks * 32 + q * 8];
      f16x8 af;
#pragma unroll
      for (int jj = 0; jj < 8; ++jj) {
        _Float16 pp = e1.x * e2pv[jj];
        _Float16 pn = e1.y * e2nv[jj];
        _Float16 pm = pp > pn ? pp : pn;  // == exp(lrelu(s1+s2)-2)
        af[jj] = ((word >> jj) & 1u) ? pm : (_Float16)0;
      }
      const f16x8 bf =
          *(const f16x8*)((const char*)whs + bfo + (((ks * 4 + q) ^ m) << 4));
      acc = __builtin_amdgcn_mfma_f32_16x16x32_f16(af, bf, acc, 0, 0, 0);
      lf = __builtin_amdgcn_mfma_f32_16x16x32_f16(af, ones, lf, 0, 0, 0);
    }
    __syncthreads();  // all waves done reading before next ds_write
  }

  // epilogue: C-layout row = q*4+r, col = m; lf[r] = that row's FULL sum.
#pragma unroll
  for (int r = 0; r < 4; ++r) {
    const float l = lf[r];
    const float inv = (l == 0.f) ? 1.f : 1.f / l;  // fully-masked row guard
    out[((size_t)(b * N_) + i0 + q * 4 + r) * FOUT + g * 16 + m] = acc[r] * inv;
  }
}

extern "C" void kernel_launch(void* const* d_in, const int* in_sizes, int n_in,
                              void* d_out, int out_size, void* d_ws, size_t ws_size,
                              hipStream_t stream) {
  const float* h   = (const float*)d_in[0];
  const int*   adj = (const int*)d_in[1];
  const float* W   = (const float*)d_in[2];
  const float* a   = (const float*)d_in[3];
  float* out = (float*)d_out;

  // ws: WhT 2MB | e1h2 64KB | e2ps 32KB | e2ns 32KB | bits 4MB
  unsigned short* WhT = (unsigned short*)d_ws;
  unsigned int* e1h2 = (unsigned int*)(WhT + (size_t)B_ * 64 * N_);
  unsigned short* e2ps = (unsigned short*)(e1h2 + B_ * N_);
  unsigned short* e2ns = e2ps + B_ * N_;
  unsigned int* bits = (unsigned int*)(e2ns + B_ * N_);

  // 1024 wh-role blocks + 4096 pack-role blocks
  k_prep<<<dim3(5120), 256, 0, stream>>>(h, W, a, adj, WhT, e1h2, e2ps, e2ns,
                                         bits);
  k_attn<<<dim3(N_ / 16, B_), 256, 0, stream>>>(WhT, e1h2, e2ps, e2ns, bits,
                                                out);
}